// Round 27
// baseline (474.800 us; speedup 1.0000x reference)
//
#include <hip/hip_runtime.h>
#include <math.h>

#define N_NODES 20000
#define N_EDGES 256000
#define ETOT (N_EDGES + N_NODES)
#define NPAD 20096    // 314*64
#define NPAD2 40064   // 626*64
#define NBLK_SCAN ((N_NODES + 255) / 256)   // 79

typedef __attribute__((ext_vector_type(8))) short bf16x8;
typedef __attribute__((ext_vector_type(4))) float f32x4;

__device__ __forceinline__ unsigned short f2bf(float f) {
    unsigned int u = __builtin_bit_cast(unsigned int, f);
    u = (u + 0x7fff + ((u >> 16) & 1)) >> 16;
    return (unsigned short)u;
}

__device__ __forceinline__ float bf2f(unsigned short u) {
    return __builtin_bit_cast(float, (unsigned int)u << 16);
}

__device__ __forceinline__ void gload_lds16(const void* g, void* l) {
    __builtin_amdgcn_global_load_lds(
        (const __attribute__((address_space(1))) void*)g,
        (__attribute__((address_space(3))) void*)l, 16, 0, 0);
}

// unpack uint4 (8 bf16) and fma into acc[8]
__device__ __forceinline__ void fma8(float* acc, uint4 v, float w) {
    acc[0] = fmaf(w, __builtin_bit_cast(float, v.x << 16), acc[0]);
    acc[1] = fmaf(w, __builtin_bit_cast(float, v.x & 0xffff0000u), acc[1]);
    acc[2] = fmaf(w, __builtin_bit_cast(float, v.y << 16), acc[2]);
    acc[3] = fmaf(w, __builtin_bit_cast(float, v.y & 0xffff0000u), acc[3]);
    acc[4] = fmaf(w, __builtin_bit_cast(float, v.z << 16), acc[4]);
    acc[5] = fmaf(w, __builtin_bit_cast(float, v.z & 0xffff0000u), acc[5]);
    acc[6] = fmaf(w, __builtin_bit_cast(float, v.w << 16), acc[6]);
    acc[7] = fmaf(w, __builtin_bit_cast(float, v.w & 0xffff0000u), acc[7]);
}

// ---------------------------------------------------------------------------
// Edge preprocessing: counting sort by dst, deterministic order within segment
// ---------------------------------------------------------------------------

__global__ void hist_kernel(const int* __restrict__ ei, int* __restrict__ cnt) {
    for (int e = blockIdx.x * blockDim.x + threadIdx.x; e < ETOT;
         e += gridDim.x * blockDim.x) {
        int d = (e < N_EDGES) ? ei[N_EDGES + e] : (e - N_EDGES);
        atomicAdd(&cnt[d], 1);
    }
}

__global__ __launch_bounds__(256) void scanA(const int* __restrict__ cnt,
                                             int* __restrict__ incl,
                                             int* __restrict__ bsum) {
    __shared__ int sh[256];
    int t = threadIdx.x;
    int i = blockIdx.x * 256 + t;
    int v = (i < N_NODES) ? cnt[i] : 0;
    sh[t] = v;
    __syncthreads();
#pragma unroll
    for (int off = 1; off < 256; off <<= 1) {
        int u = (t >= off) ? sh[t - off] : 0;
        __syncthreads();
        sh[t] += u;
        __syncthreads();
    }
    if (i < N_NODES) incl[i] = sh[t];
    if (t == 255) bsum[blockIdx.x] = sh[255];
}

__global__ __launch_bounds__(128) void scanB(int* __restrict__ bsum,
                                             int* __restrict__ row_start) {
    __shared__ int sh[128];
    int t = threadIdx.x;
    int v = (t < NBLK_SCAN) ? bsum[t] : 0;
    sh[t] = v;
    __syncthreads();
#pragma unroll
    for (int off = 1; off < 128; off <<= 1) {
        int u = (t >= off) ? sh[t - off] : 0;
        __syncthreads();
        sh[t] += u;
        __syncthreads();
    }
    if (t < NBLK_SCAN) bsum[t] = sh[t] - v;  // exclusive
    if (t == 0) row_start[0] = 0;
}

__global__ __launch_bounds__(256) void scanC(int* __restrict__ cursor,
                                             int* __restrict__ row_start,
                                             const int* __restrict__ bsum) {
    int i = blockIdx.x * 256 + threadIdx.x;
    if (i < N_NODES) {
        int incl = row_start[i + 1] + bsum[blockIdx.x];
        row_start[i + 1] = incl;
        cursor[i] = incl - cursor[i];
    }
}

__global__ void scatter_kernel(const int* __restrict__ ei, int* __restrict__ cursor,
                               int* __restrict__ sorted_id) {
    for (int e = blockIdx.x * blockDim.x + threadIdx.x; e < ETOT;
         e += gridDim.x * blockDim.x) {
        int d = (e < N_EDGES) ? ei[N_EDGES + e] : (e - N_EDGES);
        int pos = atomicAdd(&cursor[d], 1);
        sorted_id[pos] = e;
    }
}

// Deterministic order via wave-parallel rank sort: one wave per node.
__global__ __launch_bounds__(256) void segsort_kernel(
    const int* __restrict__ ei, const int* __restrict__ row_start,
    int* __restrict__ sorted_id, int* __restrict__ sorted_src) {
    int wv = threadIdx.x >> 6, lane = threadIdx.x & 63;
    int n = blockIdx.x * 4 + wv;
    if (n >= N_NODES) return;
    int base = row_start[n];
    int deg = row_start[n + 1] - base;
    if (deg <= 64) {
        int id = (lane < deg) ? sorted_id[base + lane] : 0x7fffffff;
        int rank = 0;
        for (int j = 0; j < deg; j++) {
            int idj = __shfl(id, j);
            rank += (idj < id);
        }
        if (lane < deg) {
            int src = (id < N_EDGES) ? ei[id] : (id - N_EDGES);
            sorted_src[base + rank] = src;
        }
    } else if (lane == 0) {
        for (int i = base + 1; i < base + deg; i++) {
            int v = sorted_id[i];
            int j = i - 1;
            while (j >= base && sorted_id[j] > v) {
                sorted_id[j + 1] = sorted_id[j];
                j--;
            }
            sorted_id[j + 1] = v;
        }
        for (int i = base; i < base + deg; i++) {
            int id = sorted_id[i];
            sorted_src[i] = (id < N_EDGES) ? ei[id] : (id - N_EDGES);
        }
    }
}

// ---------------------------------------------------------------------------
// One-launch setup: cursor zeroing + pad-row zeroing + bf16 conversions
// ---------------------------------------------------------------------------
struct SetupArgs {
    const float* s[7];
    unsigned short* d[7];
    int cum[8];
    int* cursor;
    unsigned short* x16;
    unsigned short* h16n;
    unsigned short* h16wA;
    unsigned short* h16wB;
    unsigned short* xp16;
    unsigned short* st16;
    unsigned short* om16;
};

__global__ __launch_bounds__(256) void setup_all(SetupArgs a) {
    int i = blockIdx.x * 256 + threadIdx.x;
    const int PR = NPAD - N_NODES;  // 96 pad rows
    if (i < N_NODES) a.cursor[i] = 0;
    if (i < PR * 128) {
        a.x16[(size_t)N_NODES * 128 + i] = 0;
        a.h16n[(size_t)N_NODES * 128 + i] = 0;
        a.om16[(size_t)N_NODES * 128 + i] = 0;
    }
    if (i < PR * 512) {
        a.h16wA[(size_t)N_NODES * 512 + i] = 0;
        a.h16wB[(size_t)N_NODES * 512 + i] = 0;
        a.xp16[(size_t)N_NODES * 512 + i] = 0;
    }
    if (i < (NPAD2 - 2 * N_NODES) * 128) a.st16[(size_t)(2 * N_NODES) * 128 + i] = 0;
    if (i < a.cum[7]) {
        int r = 0;
        while (i >= a.cum[r + 1]) r++;
        int off = i - a.cum[r];
        a.d[r][off] = f2bf(a.s[r][off]);
    }
}

// ---------------------------------------------------------------------------
// ahat[h][k] = sum_c a[h*128+c] * W0[h*128+c][k]  (W0 bf16 [512,128])
// One block, 512 threads; thread = h*128+k computes both s and d variants.
// ---------------------------------------------------------------------------
__global__ __launch_bounds__(512) void make_ahat(
    const unsigned short* __restrict__ W016, const float* __restrict__ as0,
    const float* __restrict__ ad0, float* __restrict__ ahat_s,
    float* __restrict__ ahat_d) {
    int t = threadIdx.x;  // h*128+k
    int h = t >> 7, k = t & 127;
    float ss = 0.f, sd = 0.f;
    for (int c = 0; c < 128; c++) {
        float w = bf2f(W016[(size_t)(h * 128 + c) * 128 + k]);
        ss = fmaf(as0[h * 128 + c], w, ss);
        sd = fmaf(ad0[h * 128 + c], w, sd);
    }
    ahat_s[t] = ss;
    ahat_d[t] = sd;
}

// ---------------------------------------------------------------------------
// coef128: als[n,h] = h16n[n]·ahat_s[h], ald likewise.  Wave per node.
// ---------------------------------------------------------------------------
__global__ __launch_bounds__(256) void coef128(
    const unsigned short* __restrict__ h16n, const float* __restrict__ ahat_s,
    const float* __restrict__ ahat_d, float* __restrict__ als,
    float* __restrict__ ald) {
    int wv = threadIdx.x >> 6, lane = threadIdx.x & 63;
    int n = blockIdx.x * 4 + wv;
    if (n >= N_NODES) return;
    int k0 = 2 * lane;
    float h0 = bf2f(h16n[(size_t)n * 128 + k0]);
    float h1 = bf2f(h16n[(size_t)n * 128 + k0 + 1]);
    float accs[4], accd[4];
#pragma unroll
    for (int h = 0; h < 4; h++) {
        accs[h] = h0 * ahat_s[h * 128 + k0] + h1 * ahat_s[h * 128 + k0 + 1];
        accd[h] = h0 * ahat_d[h * 128 + k0] + h1 * ahat_d[h * 128 + k0 + 1];
    }
#pragma unroll
    for (int off = 1; off <= 32; off <<= 1) {
#pragma unroll
        for (int h = 0; h < 4; h++) {
            accs[h] += __shfl_xor(accs[h], off);
            accd[h] += __shfl_xor(accd[h], off);
        }
    }
    if (lane == 0) {
#pragma unroll
        for (int h = 0; h < 4; h++) {
            als[n * 4 + h] = accs[h];
            ald[n * 4 + h] = accd[h];
        }
    }
}

// ---------------------------------------------------------------------------
// bf16 MFMA GEMM, 64x128 tile (BK=64, 4 waves each 32x64).
// lda = A row stride (elements); adiag: A column base = blockIdx.y*K
// (block-diagonal per-head projection).  Optional fused attn-coef epilogue.
// ---------------------------------------------------------------------------
__global__ __launch_bounds__(256) void gemm_mfma(
    const unsigned short* __restrict__ A, const unsigned short* __restrict__ B,
    const float* __restrict__ bias, float* __restrict__ Cf,
    unsigned short* __restrict__ C16, int R, int K, int ldc,
    const float* __restrict__ a_s, const float* __restrict__ a_d,
    float* __restrict__ al_s, float* __restrict__ al_d, int H,
    int lda, int adiag) {
    __shared__ unsigned short Al[64 * 64];
    __shared__ unsigned short Bl[128 * 64];
    __shared__ float red_s[4][32], red_d[4][32];
    int tid = threadIdx.x;
    int lane = tid & 63, wv = tid >> 6;
    int wr = (wv >> 1) * 32, wc = (wv & 1) * 64;
    size_t br = (size_t)blockIdx.x * 64;
    size_t bc = (size_t)blockIdx.y * 128;
    int acol = adiag ? (int)blockIdx.y * K : 0;
    f32x4 acc[2][4] = {};
    for (int k0 = 0; k0 < K; k0 += 64) {
#pragma unroll
        for (int i = 0; i < 2; i++) {
            int idx = i * 256 + tid;
            int row = idx >> 3;
            int kb = (idx & 7) << 4;
            gload_lds16((const char*)(A + (br + row) * lda + acol + k0) + kb,
                        (char*)Al + idx * 16);
        }
#pragma unroll
        for (int i = 0; i < 4; i++) {
            int idx = i * 256 + tid;
            int row = idx >> 3;
            int kb = (idx & 7) << 4;
            gload_lds16((const char*)(B + (bc + row) * K + k0) + kb,
                        (char*)Bl + idx * 16);
        }
        __syncthreads();
#pragma unroll
        for (int kk = 0; kk < 2; kk++) {
            bf16x8 af[2], bfr[4];
#pragma unroll
            for (int m = 0; m < 2; m++)
                af[m] = *(const bf16x8*)&Al[(wr + m * 16 + (lane & 15)) * 64 +
                                            kk * 32 + (lane >> 4) * 8];
#pragma unroll
            for (int n = 0; n < 4; n++)
                bfr[n] = *(const bf16x8*)&Bl[(wc + n * 16 + (lane & 15)) * 64 +
                                             kk * 32 + (lane >> 4) * 8];
#pragma unroll
            for (int m = 0; m < 2; m++)
#pragma unroll
                for (int n = 0; n < 4; n++)
                    acc[m][n] = __builtin_amdgcn_mfma_f32_16x16x32_bf16(
                        af[m], bfr[n], acc[m][n], 0, 0, 0);
        }
        __syncthreads();
    }

    if (al_s) {
        float asr[4], adr[4];
#pragma unroll
        for (int n = 0; n < 4; n++) {
            int c = (int)bc + wc + n * 16 + (lane & 15);
            asr[n] = a_s[c];
            adr[n] = a_d[c];
        }
        float ps[2][4], pd[2][4];
#pragma unroll
        for (int m = 0; m < 2; m++)
#pragma unroll
            for (int j = 0; j < 4; j++) {
                float s = 0.f, d = 0.f;
#pragma unroll
                for (int n = 0; n < 4; n++) {
                    float v = acc[m][n][j];
                    s = fmaf(v, asr[n], s);
                    d = fmaf(v, adr[n], d);
                }
#pragma unroll
                for (int off = 8; off; off >>= 1) {
                    s += __shfl_xor(s, off);
                    d += __shfl_xor(d, off);
                }
                ps[m][j] = s;
                pd[m][j] = d;
            }
        if ((lane & 15) == 0) {
#pragma unroll
            for (int m = 0; m < 2; m++)
#pragma unroll
                for (int j = 0; j < 4; j++) {
                    int lr = m * 16 + (lane >> 4) * 4 + j;  // 0..31
                    red_s[wv][lr] = ps[m][j];
                    red_d[wv][lr] = pd[m][j];
                }
        }
        __syncthreads();
        if (tid < 64) {
            int half = tid >> 5, lr = tid & 31;
            float s = red_s[half * 2][lr] + red_s[half * 2 + 1][lr];
            float d = red_d[half * 2][lr] + red_d[half * 2 + 1][lr];
            size_t r = br + half * 32 + lr;
            if (r < (size_t)R) {
                al_s[r * H + blockIdx.y] = s;
                al_d[r * H + blockIdx.y] = d;
            }
        }
    }

#pragma unroll
    for (int m = 0; m < 2; m++) {
        int r0 = wr + m * 16 + (lane >> 4) * 4;
#pragma unroll
        for (int n = 0; n < 4; n++) {
            int c = (int)bc + wc + n * 16 + (lane & 15);
            float bv = bias ? bias[c] : 0.f;
#pragma unroll
            for (int j = 0; j < 4; j++) {
                size_t r = br + r0 + j;
                if (r < (size_t)R) {
                    float v = acc[m][n][j] + bv;
                    if (Cf) Cf[r * ldc + c] = v;
                    if (C16) C16[r * ldc + c] = f2bf(v);
                }
            }
        }
    }
}

// ---------------------------------------------------------------------------
// Wave-per-node GAT aggregation for C=512 (4 heads): one wave owns one node.
// ---------------------------------------------------------------------------
template <int RES>
__global__ __launch_bounds__(256) void gat_agg512(
    const unsigned short* __restrict__ xp16, const float* __restrict__ al_s,
    const float* __restrict__ al_d, const int* __restrict__ row_start,
    const int* __restrict__ srcs, const float* __restrict__ bias,
    const float* __restrict__ gamma, const float* __restrict__ beta,
    const unsigned short* __restrict__ h_res16, unsigned short* __restrict__ out16) {
    const int C = 512;
    int tid = threadIdx.x;
    int lane = tid & 63, wv = tid >> 6;
    int n = blockIdx.x * 4 + wv;
    __shared__ int offw[4][64];
    __shared__ float logw[4][256];
    if (n >= N_NODES) return;
    int base = row_start[n];
    int deg = row_start[n + 1] - base;
    int head = lane >> 4;

    float acc[8] = {};
    float scale_end;

    if (deg <= 64) {
        int e_ = lane >> 2, h_ = lane & 3;
        float m = -3.4e38f;
        for (int e0 = 0; e0 < deg; e0 += 16) {
            int e = e0 + e_;
            float v = -3.4e38f;
            if (e < deg) {
                int src = srcs[base + e];
                if (h_ == 0) offw[wv][e] = src * (C * 2);
                float t = al_s[src * 4 + h_] + al_d[n * 4 + h_];
                v = t > 0.f ? t : 0.2f * t;
                logw[wv][e * 4 + h_] = v;
            }
            m = fmaxf(m, v);
        }
#pragma unroll
        for (int off = 4; off <= 32; off <<= 1) m = fmaxf(m, __shfl_xor(m, off));
        float s = 0.f;
        for (int e0 = 0; e0 < deg; e0 += 16) {
            int e = e0 + e_;
            if (e < deg) {
                float p = __expf(logw[wv][e * 4 + h_] - m);
                logw[wv][e * 4 + h_] = p;
                s += p;
            }
        }
#pragma unroll
        for (int off = 4; off <= 32; off <<= 1) s += __shfl_xor(s, off);
        float inv = 1.0f / (s + 1e-16f);
        scale_end = __shfl(inv, head);
        const char* xb = (const char*)xp16 + lane * 16;
#pragma unroll 4
        for (int j = 0; j < deg; j++) {
            float w = logw[wv][j * 4 + head];
            uint4 vv = *(const uint4*)(xb + offw[wv][j]);
            fma8(acc, vv, w);
        }
    } else {
        int e_ = lane >> 2, h_ = lane & 3;
        float m = -3.4e38f;
        for (int e0 = 0; e0 < deg; e0 += 16) {
            int e = e0 + e_;
            if (e < deg) {
                int src = srcs[base + e];
                float t = al_s[src * 4 + h_] + al_d[n * 4 + h_];
                t = t > 0.f ? t : 0.2f * t;
                m = fmaxf(m, t);
            }
        }
#pragma unroll
        for (int off = 4; off <= 32; off <<= 1) m = fmaxf(m, __shfl_xor(m, off));
        float s = 0.f;
        for (int e0 = 0; e0 < deg; e0 += 16) {
            int e = e0 + e_;
            if (e < deg) {
                int src = srcs[base + e];
                float t = al_s[src * 4 + h_] + al_d[n * 4 + h_];
                t = t > 0.f ? t : 0.2f * t;
                s += __expf(t - m);
            }
        }
#pragma unroll
        for (int off = 4; off <= 32; off <<= 1) s += __shfl_xor(s, off);
        float mg = __shfl(m, head);
        float sg = __shfl(s, head);
        float invg = 1.0f / (sg + 1e-16f);
        float aldh = al_d[n * 4 + head];
        const char* xb = (const char*)xp16 + lane * 16;
        for (int j = 0; j < deg; j++) {
            int src = srcs[base + j];
            float t = al_s[src * 4 + head] + aldh;
            t = t > 0.f ? t : 0.2f * t;
            float w = __expf(t - mg) * invg;
            uint4 vv = *(const uint4*)(xb + (size_t)src * (C * 2));
            fma8(acc, vv, w);
        }
        scale_end = 1.0f;
    }

    // ---- epilogue: scale, +bias, ELU, LayerNorm (64-lane), residual ----
    int ch0 = 8 * lane;
    float vals[8];
    {
        float4 b0 = *(const float4*)&bias[ch0];
        float4 b1 = *(const float4*)&bias[ch0 + 4];
        vals[0] = acc[0] * scale_end + b0.x;
        vals[1] = acc[1] * scale_end + b0.y;
        vals[2] = acc[2] * scale_end + b0.z;
        vals[3] = acc[3] * scale_end + b0.w;
        vals[4] = acc[4] * scale_end + b1.x;
        vals[5] = acc[5] * scale_end + b1.y;
        vals[6] = acc[6] * scale_end + b1.z;
        vals[7] = acc[7] * scale_end + b1.w;
    }
    float s2 = 0.f, q = 0.f;
#pragma unroll
    for (int k = 0; k < 8; k++) {
        vals[k] = vals[k] > 0.f ? vals[k] : (__expf(vals[k]) - 1.0f);
        s2 += vals[k];
        q += vals[k] * vals[k];
    }
#pragma unroll
    for (int off = 1; off <= 32; off <<= 1) {
        s2 += __shfl_xor(s2, off);
        q += __shfl_xor(q, off);
    }
    float mu = s2 / C;
    float var = q / C - mu * mu;
    float rstd = 1.0f / sqrtf(var + 1e-5f);
    {
        float4 g0 = *(const float4*)&gamma[ch0];
        float4 g1 = *(const float4*)&gamma[ch0 + 4];
        float4 be0v = *(const float4*)&beta[ch0];
        float4 be1v = *(const float4*)&beta[ch0 + 4];
        float gg[8] = {g0.x, g0.y, g0.z, g0.w, g1.x, g1.y, g1.z, g1.w};
        float bb[8] = {be0v.x, be0v.y, be0v.z, be0v.w,
                       be1v.x, be1v.y, be1v.z, be1v.w};
#pragma unroll
        for (int k = 0; k < 8; k++) vals[k] = (vals[k] - mu) * rstd * gg[k] + bb[k];
    }
    if (RES == 1) {
        ushort4 r0 = *(const ushort4*)&h_res16[(size_t)n * C + ch0];
        ushort4 r1 = *(const ushort4*)&h_res16[(size_t)n * C + ch0 + 4];
        vals[0] += bf2f(r0.x); vals[1] += bf2f(r0.y);
        vals[2] += bf2f(r0.z); vals[3] += bf2f(r0.w);
        vals[4] += bf2f(r1.x); vals[5] += bf2f(r1.y);
        vals[6] += bf2f(r1.z); vals[7] += bf2f(r1.w);
    }
    uint4 pk;
    pk.x = (unsigned)f2bf(vals[0]) | ((unsigned)f2bf(vals[1]) << 16);
    pk.y = (unsigned)f2bf(vals[2]) | ((unsigned)f2bf(vals[3]) << 16);
    pk.z = (unsigned)f2bf(vals[4]) | ((unsigned)f2bf(vals[5]) << 16);
    pk.w = (unsigned)f2bf(vals[6]) | ((unsigned)f2bf(vals[7]) << 16);
    *(uint4*)&out16[(size_t)n * C + ch0] = pk;
}

// ---------------------------------------------------------------------------
// Layer-0 aggregate-then-project gather: wave per node; gathers 128-ch h rows
// (256B, shared across the 4 head-groups of lanes) into s[n, head, k] where
// lane owns s channels head*128 + (lane&15)*8 .. +7 == 8*lane.  No epilogue.
// ---------------------------------------------------------------------------
__global__ __launch_bounds__(256) void gat_gather128(
    const unsigned short* __restrict__ h16n, const float* __restrict__ al_s,
    const float* __restrict__ al_d, const int* __restrict__ row_start,
    const int* __restrict__ srcs, unsigned short* __restrict__ s16) {
    int tid = threadIdx.x;
    int lane = tid & 63, wv = tid >> 6;
    int n = blockIdx.x * 4 + wv;
    __shared__ int offw[4][64];
    __shared__ float logw[4][256];
    if (n >= N_NODES) return;
    int base = row_start[n];
    int deg = row_start[n + 1] - base;
    int head = lane >> 4;
    int li = lane & 15;

    float acc[8] = {};
    float scale_end;

    if (deg <= 64) {
        int e_ = lane >> 2, h_ = lane & 3;
        float m = -3.4e38f;
        for (int e0 = 0; e0 < deg; e0 += 16) {
            int e = e0 + e_;
            float v = -3.4e38f;
            if (e < deg) {
                int src = srcs[base + e];
                if (h_ == 0) offw[wv][e] = src * 256;  // 128 ch bf16 = 256 B
                float t = al_s[src * 4 + h_] + al_d[n * 4 + h_];
                v = t > 0.f ? t : 0.2f * t;
                logw[wv][e * 4 + h_] = v;
            }
            m = fmaxf(m, v);
        }
#pragma unroll
        for (int off = 4; off <= 32; off <<= 1) m = fmaxf(m, __shfl_xor(m, off));
        float s = 0.f;
        for (int e0 = 0; e0 < deg; e0 += 16) {
            int e = e0 + e_;
            if (e < deg) {
                float p = __expf(logw[wv][e * 4 + h_] - m);
                logw[wv][e * 4 + h_] = p;
                s += p;
            }
        }
#pragma unroll
        for (int off = 4; off <= 32; off <<= 1) s += __shfl_xor(s, off);
        float inv = 1.0f / (s + 1e-16f);
        scale_end = __shfl(inv, head);
        const char* xb = (const char*)h16n + li * 16;
#pragma unroll 4
        for (int j = 0; j < deg; j++) {
            float w = logw[wv][j * 4 + head];
            uint4 vv = *(const uint4*)(xb + offw[wv][j]);
            fma8(acc, vv, w);
        }
    } else {
        int e_ = lane >> 2, h_ = lane & 3;
        float m = -3.4e38f;
        for (int e0 = 0; e0 < deg; e0 += 16) {
            int e = e0 + e_;
            if (e < deg) {
                int src = srcs[base + e];
                float t = al_s[src * 4 + h_] + al_d[n * 4 + h_];
                t = t > 0.f ? t : 0.2f * t;
                m = fmaxf(m, t);
            }
        }
#pragma unroll
        for (int off = 4; off <= 32; off <<= 1) m = fmaxf(m, __shfl_xor(m, off));
        float s = 0.f;
        for (int e0 = 0; e0 < deg; e0 += 16) {
            int e = e0 + e_;
            if (e < deg) {
                int src = srcs[base + e];
                float t = al_s[src * 4 + h_] + al_d[n * 4 + h_];
                t = t > 0.f ? t : 0.2f * t;
                s += __expf(t - m);
            }
        }
#pragma unroll
        for (int off = 4; off <= 32; off <<= 1) s += __shfl_xor(s, off);
        float mg = __shfl(m, head);
        float sg = __shfl(s, head);
        float invg = 1.0f / (sg + 1e-16f);
        float aldh = al_d[n * 4 + head];
        const char* xb = (const char*)h16n + li * 16;
        for (int j = 0; j < deg; j++) {
            int src = srcs[base + j];
            float t = al_s[src * 4 + head] + aldh;
            t = t > 0.f ? t : 0.2f * t;
            float w = __expf(t - mg) * invg;
            uint4 vv = *(const uint4*)(xb + (size_t)src * 256);
            fma8(acc, vv, w);
        }
        scale_end = 1.0f;
    }

    uint4 pk;
    pk.x = (unsigned)f2bf(acc[0] * scale_end) | ((unsigned)f2bf(acc[1] * scale_end) << 16);
    pk.y = (unsigned)f2bf(acc[2] * scale_end) | ((unsigned)f2bf(acc[3] * scale_end) << 16);
    pk.z = (unsigned)f2bf(acc[4] * scale_end) | ((unsigned)f2bf(acc[5] * scale_end) << 16);
    pk.w = (unsigned)f2bf(acc[6] * scale_end) | ((unsigned)f2bf(acc[7] * scale_end) << 16);
    *(uint4*)&s16[(size_t)n * 512 + 8 * lane] = pk;
}

// ---------------------------------------------------------------------------
// ln512: vals = LN(ELU(proj + bias)) * gamma + beta  (no residual), wave/node.
// ---------------------------------------------------------------------------
__global__ __launch_bounds__(256) void ln512(
    const unsigned short* __restrict__ proj16, const float* __restrict__ bias,
    const float* __restrict__ gamma, const float* __restrict__ beta,
    unsigned short* __restrict__ out16) {
    const int C = 512;
    int lane = threadIdx.x & 63, wv = threadIdx.x >> 6;
    int n = blockIdx.x * 4 + wv;
    if (n >= N_NODES) return;
    int ch0 = 8 * lane;
    uint4 pv = *(const uint4*)&proj16[(size_t)n * C + ch0];
    float4 b0 = *(const float4*)&bias[ch0];
    float4 b1 = *(const float4*)&bias[ch0 + 4];
    float vals[8];
    vals[0] = __builtin_bit_cast(float, pv.x << 16) + b0.x;
    vals[1] = __builtin_bit_cast(float, pv.x & 0xffff0000u) + b0.y;
    vals[2] = __builtin_bit_cast(float, pv.y << 16) + b0.z;
    vals[3] = __builtin_bit_cast(float, pv.y & 0xffff0000u) + b0.w;
    vals[4] = __builtin_bit_cast(float, pv.z << 16) + b1.x;
    vals[5] = __builtin_bit_cast(float, pv.z & 0xffff0000u) + b1.y;
    vals[6] = __builtin_bit_cast(float, pv.w << 16) + b1.z;
    vals[7] = __builtin_bit_cast(float, pv.w & 0xffff0000u) + b1.w;
    float s2 = 0.f, q = 0.f;
#pragma unroll
    for (int k = 0; k < 8; k++) {
        vals[k] = vals[k] > 0.f ? vals[k] : (__expf(vals[k]) - 1.0f);
        s2 += vals[k];
        q += vals[k] * vals[k];
    }
#pragma unroll
    for (int off = 1; off <= 32; off <<= 1) {
        s2 += __shfl_xor(s2, off);
        q += __shfl_xor(q, off);
    }
    float mu = s2 / C;
    float var = q / C - mu * mu;
    float rstd = 1.0f / sqrtf(var + 1e-5f);
    float4 g0 = *(const float4*)&gamma[ch0];
    float4 g1 = *(const float4*)&gamma[ch0 + 4];
    float4 be0v = *(const float4*)&beta[ch0];
    float4 be1v = *(const float4*)&beta[ch0 + 4];
    float gg[8] = {g0.x, g0.y, g0.z, g0.w, g1.x, g1.y, g1.z, g1.w};
    float bb[8] = {be0v.x, be0v.y, be0v.z, be0v.w, be1v.x, be1v.y, be1v.z, be1v.w};
#pragma unroll
    for (int k = 0; k < 8; k++) vals[k] = (vals[k] - mu) * rstd * gg[k] + bb[k];
    uint4 pk;
    pk.x = (unsigned)f2bf(vals[0]) | ((unsigned)f2bf(vals[1]) << 16);
    pk.y = (unsigned)f2bf(vals[2]) | ((unsigned)f2bf(vals[3]) << 16);
    pk.z = (unsigned)f2bf(vals[4]) | ((unsigned)f2bf(vals[5]) << 16);
    pk.w = (unsigned)f2bf(vals[6]) | ((unsigned)f2bf(vals[7]) << 16);
    *(uint4*)&out16[(size_t)n * C + ch0] = pk;
}

// ---------------------------------------------------------------------------
// C=128, 1-head aggregation (one wave per node, 16 lanes/row, 4 edge groups)
// ---------------------------------------------------------------------------
__global__ __launch_bounds__(64) void gat_agg128(
    const unsigned short* __restrict__ xp16, const float* __restrict__ al_s,
    const float* __restrict__ al_d, const int* __restrict__ row_start,
    const int* __restrict__ srcs, const float* __restrict__ bias,
    const float* __restrict__ gamma, const float* __restrict__ beta,
    const unsigned short* __restrict__ h_res16, unsigned short* __restrict__ out16,
    unsigned short* __restrict__ out2_16, int out2_stride) {
    const int C = 128;
    int n = blockIdx.x;
    int lane = threadIdx.x & 63;
    __shared__ int off_sh[64];
    __shared__ float w_sh[64];
    __shared__ float m_sh, s_sh;
    int base = row_start[n];
    int deg = row_start[n + 1] - base;

    float acc[8] = {};

    if (deg <= 64) {
        float v = -3.4e38f;
        if (lane < deg) {
            int src = srcs[base + lane];
            off_sh[lane] = src * (C * 2);
            float t = al_s[src] + al_d[n];
            v = t > 0.f ? t : 0.2f * t;
        }
        float m = v;
#pragma unroll
        for (int off = 32; off; off >>= 1) m = fmaxf(m, __shfl_xor(m, off));
        float p = (lane < deg) ? __expf(v - m) : 0.f;
        float s = p;
#pragma unroll
        for (int off = 32; off; off >>= 1) s += __shfl_xor(s, off);
        s += 1e-16f;
        if (lane < deg) w_sh[lane] = p / s;
        __syncthreads();
        int li = lane & 15, rg = lane >> 4;
        const char* xb = (const char*)xp16 + li * 16;
        for (int j = rg; j < deg; j += 4) {
            uint4 vv = *(const uint4*)(xb + off_sh[j]);
            fma8(acc, vv, w_sh[j]);
        }
    } else {
        float ald = al_d[n];
        float m = -3.4e38f;
        for (int e = lane; e < deg; e += 64) {
            float v = al_s[srcs[base + e]] + ald;
            v = v > 0.f ? v : 0.2f * v;
            m = fmaxf(m, v);
        }
#pragma unroll
        for (int off = 32; off; off >>= 1) m = fmaxf(m, __shfl_xor(m, off));
        float s = 0.f;
        for (int e = lane; e < deg; e += 64) {
            float v = al_s[srcs[base + e]] + ald;
            v = v > 0.f ? v : 0.2f * v;
            s += __expf(v - m);
        }
#pragma unroll
        for (int off = 32; off; off >>= 1) s += __shfl_xor(s, off);
        if (lane == 0) { m_sh = m; s_sh = s + 1e-16f; }
        __syncthreads();
        float mh = m_sh, ssh = s_sh;
        int li = lane & 15, rg = lane >> 4;
        const char* xb = (const char*)xp16 + li * 16;
        for (int j = rg; j < deg; j += 4) {
            int src = srcs[base + j];
            float t = al_s[src] + ald;
            t = t > 0.f ? t : 0.2f * t;
            float w = __expf(t - mh) / ssh;
            uint4 vv = *(const uint4*)(xb + (size_t)src * (C * 2));
            fma8(acc, vv, w);
        }
    }

    // combine 4 edge-groups via shfl; 8 ch/lane epilogue
#pragma unroll
    for (int k = 0; k < 8; k++) {
        acc[k] += __shfl_xor(acc[k], 16);
        acc[k] += __shfl_xor(acc[k], 32);
    }
    int li = lane & 15;
    int ch0 = 8 * li;
    float vals[8];
    float4 b0 = *(const float4*)&bias[ch0];
    float4 b1 = *(const float4*)&bias[ch0 + 4];
    vals[0] = acc[0] + b0.x; vals[1] = acc[1] + b0.y;
    vals[2] = acc[2] + b0.z; vals[3] = acc[3] + b0.w;
    vals[4] = acc[4] + b1.x; vals[5] = acc[5] + b1.y;
    vals[6] = acc[6] + b1.z; vals[7] = acc[7] + b1.w;
    float s = 0.f, q = 0.f;
#pragma unroll
    for (int k = 0; k < 8; k++) {
        vals[k] = vals[k] > 0.f ? vals[k] : (__expf(vals[k]) - 1.0f);
        s += vals[k];
        q += vals[k] * vals[k];
    }
#pragma unroll
    for (int off = 8; off; off >>= 1) {
        s += __shfl_xor(s, off);
        q += __shfl_xor(q, off);
    }
    float mu = s / C;
    float var = q / C - mu * mu;
    float rstd = 1.0f / sqrtf(var + 1e-5f);
    float4 g0 = *(const float4*)&gamma[ch0];
    float4 g1 = *(const float4*)&gamma[ch0 + 4];
    float4 be0v = *(const float4*)&beta[ch0];
    float4 be1v = *(const float4*)&beta[ch0 + 4];
    float gg[8] = {g0.x, g0.y, g0.z, g0.w, g1.x, g1.y, g1.z, g1.w};
    float bb[8] = {be0v.x, be0v.y, be0v.z, be0v.w, be1v.x, be1v.y, be1v.z, be1v.w};
#pragma unroll
    for (int k = 0; k < 8; k++) vals[k] = (vals[k] - mu) * rstd * gg[k] + bb[k];
    {
        const unsigned short* r = &h_res16[(size_t)n * 512 + 4 * ch0];
#pragma unroll
        for (int k = 0; k < 8; k++) {
            ushort4 rv = *(const ushort4*)&r[4 * k];
            vals[k] += 0.25f * (bf2f(rv.x) + bf2f(rv.y) + bf2f(rv.z) + bf2f(rv.w));
        }
    }
    if (lane < 16) {
        uint4 pk;
        pk.x = (unsigned)f2bf(vals[0]) | ((unsigned)f2bf(vals[1]) << 16);
        pk.y = (unsigned)f2bf(vals[2]) | ((unsigned)f2bf(vals[3]) << 16);
        pk.z = (unsigned)f2bf(vals[4]) | ((unsigned)f2bf(vals[5]) << 16);
        pk.w = (unsigned)f2bf(vals[6]) | ((unsigned)f2bf(vals[7]) << 16);
        if (out16) *(uint4*)&out16[(size_t)n * C + ch0] = pk;
        if (out2_16) *(uint4*)&out2_16[(size_t)n * out2_stride + ch0] = pk;
    }
}

// ---------------------------------------------------------------------------
// Temporal self-attention over T=2 states. qkv16:[2N,384] bf16 -> om16 bf16
// ---------------------------------------------------------------------------
__global__ __launch_bounds__(128) void temporal_attn(
    const unsigned short* __restrict__ qkv16, unsigned short* __restrict__ om16) {
    __shared__ float sh[768];
    int n = blockIdx.x;
    int c = threadIdx.x;
    for (int i = c; i < 768; i += 128) {
        int t = i / 384;
        sh[i] = bf2f(qkv16[(size_t)(n * 2 + t) * 384 + (i - t * 384)]);
    }
    __syncthreads();
    int head = c >> 5;
    int hb = head * 32;
    const float scale = 0.17677669529663687f;
    float o[2];
#pragma unroll
    for (int qt = 0; qt < 2; qt++) {
        float s0 = 0.f, s1 = 0.f;
#pragma unroll
        for (int d = 0; d < 32; d++) {
            float qv = sh[qt * 384 + hb + d];
            s0 = fmaf(qv, sh[0 * 384 + 128 + hb + d], s0);
            s1 = fmaf(qv, sh[1 * 384 + 128 + hb + d], s1);
        }
        s0 *= scale; s1 *= scale;
        float m = fmaxf(s0, s1);
        float p0 = __expf(s0 - m), p1 = __expf(s1 - m);
        float inv = 1.0f / (p0 + p1);
        o[qt] = p0 * inv * sh[0 * 384 + 256 + c] + p1 * inv * sh[1 * 384 + 256 + c];
    }
    om16[(size_t)n * 128 + c] = f2bf(0.5f * (o[0] + o[1]));
}

// ---------------------------------------------------------------------------

extern "C" void kernel_launch(void* const* d_in, const int* in_sizes, int n_in,
                              void* d_out, int out_size, void* d_ws, size_t ws_size,
                              hipStream_t stream) {
    const float* x   = (const float*)d_in[0];
    const int*   ei  = (const int*)d_in[1];
    const float* Wp  = (const float*)d_in[2];
    const float* bp  = (const float*)d_in[3];
    const float* W0  = (const float*)d_in[4];
    const float* as0 = (const float*)d_in[5];
    const float* ad0 = (const float*)d_in[6];
    const float* b0  = (const float*)d_in[7];
    const float* W1  = (const float*)d_in[8];
    const float* as1 = (const float*)d_in[9];
    const float* ad1 = (const float*)d_in[10];
    const float* b1  = (const float*)d_in[11];
    const float* W2  = (const float*)d_in[12];
    const float* as2 = (const float*)d_in[13];
    const float* ad2 = (const float*)d_in[14];
    const float* b2  = (const float*)d_in[15];
    const float* g0  = (const float*)d_in[16];
    const float* be0 = (const float*)d_in[17];
    const float* g1  = (const float*)d_in[18];
    const float* be1 = (const float*)d_in[19];
    const float* g2  = (const float*)d_in[20];
    const float* be2 = (const float*)d_in[21];
    const float* Wqkv = (const float*)d_in[22];
    const float* bqkv = (const float*)d_in[23];
    const float* Wo  = (const float*)d_in[24];
    const float* bo  = (const float*)d_in[25];
    float* out = (float*)d_out;

    const int N = N_NODES;
    float* f = (float*)d_ws;
    // fp32 buffers
    float* als = f;                        // [N,4]
    float* ald = als + (size_t)N * 4;      // [N,4]
    float* ahat_s = ald + (size_t)N * 4;   // [512]
    float* ahat_d = ahat_s + 512;          // [512]
    // int buffers
    int* row_start  = (int*)(ahat_d + 512);
    int* cursor     = row_start + (N + 1);
    int* sorted_id  = cursor + N;
    int* sorted_src = sorted_id + ETOT;
    int* bsum       = sorted_src + ETOT;          // NBLK_SCAN
    // bf16 buffers (aligned to 64B)
    uintptr_t pa = (uintptr_t)(bsum + NBLK_SCAN + 1);
    pa = (pa + 63) & ~(uintptr_t)63;
    unsigned short* x16   = (unsigned short*)pa;
    unsigned short* h16n  = x16 + (size_t)NPAD * 128;         // [NPAD,128]
    unsigned short* h16wA = h16n + (size_t)NPAD * 128;        // [NPAD,512]
    unsigned short* h16wB = h16wA + (size_t)NPAD * 512;       // [NPAD,512]
    unsigned short* xp16  = h16wB + (size_t)NPAD * 512;       // [NPAD,512] (= s16)
    unsigned short* st16  = xp16 + (size_t)NPAD * 512;        // [NPAD2,128]
    unsigned short* qkv16 = st16 + (size_t)NPAD2 * 128;       // [NPAD2,384]
    unsigned short* om16  = qkv16 + (size_t)NPAD2 * 384;      // [NPAD,128]
    unsigned short* w16   = om16 + (size_t)NPAD * 128;
    unsigned short* Wp16   = w16;
    unsigned short* W016   = Wp16 + 128 * 128;
    unsigned short* W116   = W016 + 512 * 128;
    unsigned short* W216   = W116 + 512 * 512;
    unsigned short* Wqkv16 = W216 + 128 * 512;
    unsigned short* Wo16   = Wqkv16 + 384 * 128;

    // ---- one-launch setup: cursor zero + pad zero + bf16 conversions ----
    {
        SetupArgs a;
        const float* srcs7[7] = {Wp, W0, W1, W2, Wqkv, Wo, x};
        unsigned short* dsts7[7] = {Wp16, W016, W116, W216, Wqkv16, Wo16, x16};
        int sizes7[7] = {128 * 128, 512 * 128, 512 * 512, 128 * 512,
                         384 * 128, 128 * 128, N_NODES * 128};
        int c = 0;
        a.cum[0] = 0;
        for (int i = 0; i < 7; i++) {
            a.s[i] = srcs7[i];
            a.d[i] = dsts7[i];
            c += sizes7[i];
            a.cum[i + 1] = c;
        }
        a.cursor = cursor;
        a.x16 = x16; a.h16n = h16n; a.h16wA = h16wA; a.h16wB = h16wB;
        a.xp16 = xp16; a.st16 = st16; a.om16 = om16;
        setup_all<<<(c + 255) / 256, 256, 0, stream>>>(a);
    }
    make_ahat<<<1, 512, 0, stream>>>(W016, as0, ad0, ahat_s, ahat_d);

    // ---- edge preprocessing (deterministic counting sort by dst) ----
    hist_kernel<<<1024, 256, 0, stream>>>(ei, cursor);
    scanA<<<NBLK_SCAN, 256, 0, stream>>>(cursor, row_start + 1, bsum);
    scanB<<<1, 128, 0, stream>>>(bsum, row_start);
    scanC<<<NBLK_SCAN, 256, 0, stream>>>(cursor, row_start, bsum);
    scatter_kernel<<<1024, 256, 0, stream>>>(ei, cursor, sorted_id);
    segsort_kernel<<<(N + 3) / 4, 256, 0, stream>>>(ei, row_start, sorted_id,
                                                    sorted_src);

    const int GX = NPAD / 64;   // 314
    const int GX2 = NPAD2 / 64; // 626
    const int GA = (N + 3) / 4; // 5000 blocks (wave-per-node kernels)
    // ---- input projection -> h16n ----
    {
        dim3 g(GX, 1);
        gemm_mfma<<<g, 256, 0, stream>>>(x16, Wp16, bp, nullptr, h16n, N, 128, 128,
                                         nullptr, nullptr, nullptr, nullptr, 0,
                                         128, 0);
    }

    for (int t = 0; t < 2; t++) {
        // layer 0 (aggregate-then-project): coef -> gather -> proj -> LN
        {
            coef128<<<GA, 256, 0, stream>>>(h16n, ahat_s, ahat_d, als, ald);
            gat_gather128<<<GA, 256, 0, stream>>>(h16n, als, ald, row_start,
                                                  sorted_src, xp16);
            dim3 g(GX, 4);
            gemm_mfma<<<g, 256, 0, stream>>>(xp16, W016, nullptr, nullptr, h16wB,
                                             N, 128, 512, nullptr, nullptr,
                                             nullptr, nullptr, 0, 512, 1);
            ln512<<<GA, 256, 0, stream>>>(h16wB, b0, g0, be0, h16wA);
        }
        // layer 1: 512 -> 512 (4 heads), residual = h16wA
        {
            dim3 g(GX, 4);
            gemm_mfma<<<g, 256, 0, stream>>>(h16wA, W116, nullptr, nullptr, xp16,
                                             N, 512, 512, as1, ad1, als, ald, 4,
                                             512, 0);
            gat_agg512<1><<<GA, 256, 0, stream>>>(
                xp16, als, ald, row_start, sorted_src, b1, g1, be1, h16wA, h16wB);
        }
        // layer 2: 512 -> 128 (1 head), pooled residual = h16wB
        {
            dim3 g(GX, 1);
            gemm_mfma<<<g, 256, 0, stream>>>(h16wB, W216, nullptr, nullptr, xp16,
                                             N, 512, 128, as2, ad2, als, ald, 1,
                                             512, 0);
            gat_agg128<<<N, 64, 0, stream>>>(
                xp16, als, ald, row_start, sorted_src, b2, g2, be2, h16wB,
                (t == 0) ? h16n : nullptr, st16 + (size_t)t * 128, 256);
        }
    }

    // ---- temporal attention ----
    {
        dim3 g(GX2, 3);
        gemm_mfma<<<g, 256, 0, stream>>>(st16, Wqkv16, bqkv, nullptr, qkv16,
                                         2 * N, 128, 384, nullptr, nullptr,
                                         nullptr, nullptr, 0, 128, 0);
    }
    temporal_attn<<<N, 128, 0, stream>>>(qkv16, om16);
    {
        dim3 g(GX, 1);
        gemm_mfma<<<g, 256, 0, stream>>>(om16, Wo16, bo, out, nullptr,
                                         N, 128, 128, nullptr, nullptr,
                                         nullptr, nullptr, 0, 128, 0);
    }
}